// Round 2
// baseline (1597.061 us; speedup 1.0000x reference)
//
#include <hip/hip_runtime.h>

// Sizes
constexpr int BB = 8;
constexpr int CC = 256;
constexpr int HH = 128;
constexpr int WW = 128;
constexpr int INTER = 64;
constexpr size_t NPIX = (size_t)HH * WW;            // 16384
constexpr size_t C64SZ = (size_t)BB * INTER * NPIX; // 8,388,608
constexpr size_t QSZ   = (size_t)BB * 8 * NPIX;     // 1,048,576
constexpr size_t STATSZ = (size_t)BB * HH * WW;     // 131,072
constexpr size_t OUTHALF = (size_t)BB * CC * NPIX;  // 33,554,432
constexpr size_t WT_ELEMS = (size_t)9 * 64 * 256;   // 147456 (same for head & tail)

typedef __attribute__((ext_vector_type(8))) __bf16 bf16x8;
typedef __attribute__((ext_vector_type(4))) float f32x4;
typedef __attribute__((ext_vector_type(4))) short short4v;

__device__ inline short f2bf(float f) {
    union { float f; unsigned u; } a; a.f = f;
    unsigned r = a.u + 0x7fffu + ((a.u >> 16) & 1u);   // RNE
    return (short)(r >> 16);
}

// ---------------------------------------------------------------------------
// Weight transform: wgt fp32 [OC][IC][3][3] -> wt bf16 [pos=dh*3+dw][OC][IC]
// ---------------------------------------------------------------------------
__global__ __launch_bounds__(256) void wprep_kernel(
    const float* __restrict__ wgt, short* __restrict__ wt, int OC, int IC)
{
    int idx = blockIdx.x * 256 + threadIdx.x;
    int n = 9 * OC * IC;
    if (idx >= n) return;
    int ic = idx & (IC - 1);
    int t  = idx / IC;
    int oc = t & (OC - 1);
    int pos = t / OC;
    wt[idx] = f2bf(wgt[((size_t)oc * IC + ic) * 9 + pos]);
}

// ---------------------------------------------------------------------------
// Conv 3x3 (pad 1) + BN + ReLU via bf16 MFMA implicit GEMM.
// Pipelined: prefetch next 32-ic chunk into regs (float4 loads, in-thread
// 4ic x 4pix transpose) while MFMAs run on the current chunk.
// BLK threads (BLK/64 waves): NWN waves along N, rest along OC.
// LDS: xs[row][wpos 0..129][ic 0..31 (pad to 40)] bf16 (single buffer).
// grid = (8 batches, H/R strips)
// ---------------------------------------------------------------------------
template<int IC, int OC, int R, int NT, int BLK, int MINW>
__global__ __launch_bounds__(BLK, MINW) void conv_mfma(
    const float* __restrict__ x, const short* __restrict__ wt,
    const float* __restrict__ bns, const float* __restrict__ bnb,
    float* __restrict__ out)
{
    constexpr int ROWS = R + 2;
    constexpr int NCH  = IC / 32;
    constexpr int NPIXT = R * 128;
    constexpr int NWN  = NPIXT / (NT * 16);       // waves along N
    constexpr int TOTAL_UNITS = ROWS * 8 * 32;    // (row, icq, colq)
    constexpr int NU   = TOTAL_UNITS / BLK;       // prefetch units per thread

    __shared__ __align__(16) short xs[ROWS * 130 * 40];

    const int tid = threadIdx.x;
    const int b   = blockIdx.x;
    const int h0  = blockIdx.y * R;
    const int l   = tid & 63;
    const int ln  = l & 15;
    const int q   = l >> 4;
    const int wv  = tid >> 6;
    const int nbase = (wv % NWN) * (NT * 16);
    const int oc0w  = (wv / NWN) * 64;

    f32x4 acc[4][NT];
#pragma unroll
    for (int mt = 0; mt < 4; ++mt)
#pragma unroll
        for (int nt = 0; nt < NT; ++nt)
            acc[mt][nt] = (f32x4){0.f, 0.f, 0.f, 0.f};

    const float* xb = x + (size_t)b * IC * NPIX;

    // prefetch registers: NU units of (4 ic-planes x float4 pixels)
    f32x4 pf[NU][4];

    // halo columns (gcol -1 and 128 are outside image -> zero) — invariant,
    // written once; commit never touches cols 0/129.
    if (tid < ROWS * 16) {
        int row  = tid >> 4;
        int colh = (tid & 8) ? 129 : 0;
        int icg  = tid & 7;
        short4v z; z.x = 0; z.y = 0; z.z = 0; z.w = 0;
        *(short4v*)&xs[(row * 130 + colh) * 40 + icg * 4] = z;
    }

    // ---- issue: global float4 loads for chunk ch into pf ----
    auto issue = [&](int ch) {
        const int ic0 = ch * 32;
#pragma unroll
        for (int i = 0; i < NU; ++i) {
            int u    = i * BLK + tid;
            int row  = u >> 8;          // 256 units per row (8 icq x 32 colq)
            int icq  = (u >> 5) & 7;
            int colq = u & 31;
            int grow = h0 - 1 + row;
            if ((unsigned)grow < 128u) {
                const float* p = xb + ((size_t)(ic0 + icq * 4) * 128 + grow) * 128 + colq * 4;
#pragma unroll
                for (int j = 0; j < 4; ++j)
                    pf[i][j] = *(const f32x4*)(p + (size_t)j * NPIX);
            } else {
#pragma unroll
                for (int j = 0; j < 4; ++j)
                    pf[i][j] = (f32x4){0.f, 0.f, 0.f, 0.f};
            }
        }
    };

    // ---- commit: convert + transposed LDS write (4 x ds_write_b64/unit) ----
    auto commit = [&]() {
#pragma unroll
        for (int i = 0; i < NU; ++i) {
            int u    = i * BLK + tid;
            int row  = u >> 8;
            int icq  = (u >> 5) & 7;
            int colq = u & 31;
#pragma unroll
            for (int k = 0; k < 4; ++k) {
                short4v pk;
                pk.x = f2bf(pf[i][0][k]);
                pk.y = f2bf(pf[i][1][k]);
                pk.z = f2bf(pf[i][2][k]);
                pk.w = f2bf(pf[i][3][k]);
                *(short4v*)&xs[(row * 130 + colq * 4 + k + 1) * 40 + icq * 4] = pk;
            }
        }
    };

    // prologue: stage chunk 0
    issue(0);
    commit();
    __syncthreads();

    for (int ch = 0; ch < NCH; ++ch) {
        // issue next chunk's loads so they fly under the MFMA phase
        if (ch + 1 < NCH) issue(ch + 1);

        const int ic0 = ch * 32;
        // ---- 9 accumulating GEMM positions over this 32-ic chunk ----
        for (int dh = 0; dh < 3; ++dh) {
#pragma unroll
            for (int dw = 0; dw < 3; ++dw) {
                const int pos = dh * 3 + dw;
                bf16x8 a[4];
#pragma unroll
                for (int mt = 0; mt < 4; ++mt)
                    a[mt] = *(const bf16x8*)(wt +
                        (size_t)(pos * OC + oc0w + mt * 16 + ln) * IC + ic0 + q * 8);
#pragma unroll
                for (int nt = 0; nt < NT; ++nt) {
                    int pix  = nbase + nt * 16 + ln;
                    int rowi = (pix >> 7) + dh;
                    int wpos = (pix & 127) + dw;
                    bf16x8 bfr = *(const bf16x8*)&xs[(rowi * 130 + wpos) * 40 + q * 8];
#pragma unroll
                    for (int mt = 0; mt < 4; ++mt)
                        acc[mt][nt] = __builtin_amdgcn_mfma_f32_16x16x32_bf16(
                            a[mt], bfr, acc[mt][nt], 0, 0, 0);
                }
            }
        }
        __syncthreads();
        if (ch + 1 < NCH) {
            commit();
            __syncthreads();
        }
    }

    // ---- epilogue: BN + ReLU, store fp32 NCHW ----
#pragma unroll
    for (int mt = 0; mt < 4; ++mt) {
#pragma unroll
        for (int r = 0; r < 4; ++r) {
            int oc = oc0w + mt * 16 + q * 4 + r;
            float s   = bns[oc];
            float bb2 = bnb[oc];
#pragma unroll
            for (int nt = 0; nt < NT; ++nt) {
                int pix = nbase + nt * 16 + ln;
                int h = h0 + (pix >> 7), w = pix & 127;
                float v = fmaxf(acc[mt][nt][r] * s + bb2, 0.f);
                out[(((size_t)b * OC + oc) * 128 + h) * 128 + w] = v;
            }
        }
    }
}

// ---------------------------------------------------------------------------
// QK projection: q = q_w @ xq + q_b (8 ch), k = k_w @ xe + k_b (8 ch)
// ---------------------------------------------------------------------------
__global__ __launch_bounds__(256) void qk_kernel(
    const float* __restrict__ xq, const float* __restrict__ xe,
    const float* __restrict__ qw, const float* __restrict__ qb,
    const float* __restrict__ kw, const float* __restrict__ kb,
    float* __restrict__ q, float* __restrict__ k)
{
    size_t p = (size_t)blockIdx.x * 256 + threadIdx.x;
    int b = (int)(p >> 14);
    int pix = (int)(p & 16383);
    const float* xqb = xq + (size_t)b * 64 * NPIX + pix;
    const float* xeb = xe + (size_t)b * 64 * NPIX + pix;
    float qa[8], ka[8];
#pragma unroll
    for (int o = 0; o < 8; ++o) { qa[o] = qb[o]; ka[o] = kb[o]; }
    for (int c = 0; c < 64; ++c) {
        float xv = xqb[(size_t)c * NPIX];
        float ev = xeb[(size_t)c * NPIX];
#pragma unroll
        for (int o = 0; o < 8; ++o) {
            qa[o] += qw[o * 64 + c] * xv;
            ka[o] += kw[o * 64 + c] * ev;
        }
    }
#pragma unroll
    for (int o = 0; o < 8; ++o) {
        q[((size_t)b * 8 + o) * NPIX + pix] = qa[o];
        k[((size_t)b * 8 + o) * NPIX + pix] = ka[o];
    }
}

// ---------------------------------------------------------------------------
// V projection: v = v_w @ xe + v_b (64 ch), 32 oc per z-slice
// ---------------------------------------------------------------------------
__global__ __launch_bounds__(256) void v_kernel(
    const float* __restrict__ xe,
    const float* __restrict__ vw, const float* __restrict__ vb,
    float* __restrict__ v)
{
    size_t p = (size_t)blockIdx.x * 256 + threadIdx.x;
    int b = (int)(p >> 14);
    int pix = (int)(p & 16383);
    int oc0 = blockIdx.y * 32;
    const float* xeb = xe + (size_t)b * 64 * NPIX + pix;
    float acc[32];
#pragma unroll
    for (int o = 0; o < 32; ++o) acc[o] = vb[oc0 + o];
    for (int c = 0; c < 64; ++c) {
        float ev = xeb[(size_t)c * NPIX];
#pragma unroll
        for (int o = 0; o < 32; ++o) acc[o] += vw[(oc0 + o) * 64 + c] * ev;
    }
#pragma unroll
    for (int o = 0; o < 32; ++o)
        v[((size_t)b * 64 + oc0 + o) * NPIX + pix] = acc[o];
}

// ---------------------------------------------------------------------------
// Pass 1: column attention partials.
// ---------------------------------------------------------------------------
__global__ __launch_bounds__(256) void attn_col_kernel(
    const float* __restrict__ q, const float* __restrict__ k,
    const float* __restrict__ v,
    float* __restrict__ outT, float* __restrict__ mC, float* __restrict__ sC)
{
    __shared__ float qs[8][128];
    __shared__ float ks[8][128];
    __shared__ float vs[64][129];
    __shared__ float E[32][129];

    const int tid = threadIdx.x;
    const int w = blockIdx.x;
    const int b = blockIdx.y;

    for (int i = tid; i < 1024; i += 256) {
        int c = i >> 7, h = i & 127;
        qs[c][h] = q[(((size_t)b * 8 + c) * 128 + h) * 128 + w];
        ks[c][h] = k[(((size_t)b * 8 + c) * 128 + h) * 128 + w];
    }
    for (int i = tid; i < 8192; i += 256) {
        int c = i >> 7, j = i & 127;
        vs[c][j] = v[(((size_t)b * 64 + c) * 128 + j) * 128 + w];
    }
    __syncthreads();

    const int jj = tid & 127;
    const int hi = tid >> 7;

    for (int hc = 0; hc < 4; ++hc) {
        const int h0 = hc * 32;
#pragma unroll
        for (int e = 0; e < 16; ++e) {
            int i = e * 2 + hi;
            float a = 0.f;
#pragma unroll
            for (int c = 0; c < 8; ++c) a += qs[c][h0 + i] * ks[c][jj];
            if (h0 + i == jj) a = -1e30f;
            E[i][jj] = a;
        }
        __syncthreads();
        // ---- wave-parallel softmax: 8 lanes per row, shfl_xor reduce ----
        {
            int row = tid >> 3, l8 = tid & 7;
            float m = -1e30f;
#pragma unroll
            for (int t = 0; t < 16; ++t) m = fmaxf(m, E[row][l8 + t * 8]);
            m = fmaxf(m, __shfl_xor(m, 1));
            m = fmaxf(m, __shfl_xor(m, 2));
            m = fmaxf(m, __shfl_xor(m, 4));
            float s = 0.f;
#pragma unroll
            for (int t = 0; t < 16; ++t) {
                int j = l8 + t * 8;
                float pp = __expf(E[row][j] - m);
                E[row][j] = pp;
                s += pp;
            }
            s += __shfl_xor(s, 1);
            s += __shfl_xor(s, 2);
            s += __shfl_xor(s, 4);
            if (l8 == 0) {
                mC[((size_t)b * 128 + (h0 + row)) * 128 + w] = m;
                sC[((size_t)b * 128 + (h0 + row)) * 128 + w] = s;
            }
        }
        __syncthreads();
        {
            int c0 = (tid & 15) * 4;
            int i0 = (tid >> 4) * 2;
            float acc[4][2];
#pragma unroll
            for (int a = 0; a < 4; ++a) { acc[a][0] = 0.f; acc[a][1] = 0.f; }
            for (int j = 0; j < 128; ++j) {
                float p0 = E[i0][j], p1 = E[i0 + 1][j];
#pragma unroll
                for (int a = 0; a < 4; ++a) {
                    float vv = vs[c0 + a][j];
                    acc[a][0] += vv * p0;
                    acc[a][1] += vv * p1;
                }
            }
#pragma unroll
            for (int a = 0; a < 4; ++a) {
                size_t base = (((size_t)b * 128 + w) * 64 + (c0 + a)) * 128 + h0 + i0;
                outT[base]     = acc[a][0];
                outT[base + 1] = acc[a][1];
            }
        }
        __syncthreads();
    }
}

// ---------------------------------------------------------------------------
// Pass 2: row attention partials.
// ---------------------------------------------------------------------------
__global__ __launch_bounds__(256) void attn_row_kernel(
    const float* __restrict__ q, const float* __restrict__ k,
    const float* __restrict__ v,
    float* __restrict__ outS, float* __restrict__ mR, float* __restrict__ sR)
{
    __shared__ float qs[8][128];
    __shared__ float ks[8][128];
    __shared__ float vs[64][129];
    __shared__ float E[32][129];

    const int tid = threadIdx.x;
    const int h = blockIdx.x;
    const int b = blockIdx.y;

    for (int i = tid; i < 1024; i += 256) {
        int c = i >> 7, x = i & 127;
        qs[c][x] = q[(((size_t)b * 8 + c) * 128 + h) * 128 + x];
        ks[c][x] = k[(((size_t)b * 8 + c) * 128 + h) * 128 + x];
    }
    for (int i = tid; i < 8192; i += 256) {
        int c = i >> 7, j = i & 127;
        vs[c][j] = v[(((size_t)b * 64 + c) * 128 + h) * 128 + j];
    }
    __syncthreads();

    const int jj = tid & 127;
    const int hi = tid >> 7;

    for (int wc = 0; wc < 4; ++wc) {
        const int w0 = wc * 32;
#pragma unroll
        for (int e = 0; e < 16; ++e) {
            int i = e * 2 + hi;
            float a = 0.f;
#pragma unroll
            for (int c = 0; c < 8; ++c) a += qs[c][w0 + i] * ks[c][jj];
            E[i][jj] = a;
        }
        __syncthreads();
        // ---- wave-parallel softmax ----
        {
            int row = tid >> 3, l8 = tid & 7;
            float m = -1e30f;
#pragma unroll
            for (int t = 0; t < 16; ++t) m = fmaxf(m, E[row][l8 + t * 8]);
            m = fmaxf(m, __shfl_xor(m, 1));
            m = fmaxf(m, __shfl_xor(m, 2));
            m = fmaxf(m, __shfl_xor(m, 4));
            float s = 0.f;
#pragma unroll
            for (int t = 0; t < 16; ++t) {
                int j = l8 + t * 8;
                float pp = __expf(E[row][j] - m);
                E[row][j] = pp;
                s += pp;
            }
            s += __shfl_xor(s, 1);
            s += __shfl_xor(s, 2);
            s += __shfl_xor(s, 4);
            if (l8 == 0) {
                mR[((size_t)b * 128 + h) * 128 + (w0 + row)] = m;
                sR[((size_t)b * 128 + h) * 128 + (w0 + row)] = s;
            }
        }
        __syncthreads();
        {
            int c0 = (tid & 15) * 4;
            int i0 = (tid >> 4) * 2;
            float acc[4][2];
#pragma unroll
            for (int a = 0; a < 4; ++a) { acc[a][0] = 0.f; acc[a][1] = 0.f; }
            for (int j = 0; j < 128; ++j) {
                float p0 = E[i0][j], p1 = E[i0 + 1][j];
#pragma unroll
                for (int a = 0; a < 4; ++a) {
                    float vv = vs[c0 + a][j];
                    acc[a][0] += vv * p0;
                    acc[a][1] += vv * p1;
                }
            }
#pragma unroll
            for (int a = 0; a < 4; ++a) {
                size_t base = (((size_t)b * 64 + (c0 + a)) * 128 + h) * 128 + w0 + i0;
                outS[base]     = acc[a][0];
                outS[base + 1] = acc[a][1];
            }
        }
        __syncthreads();
    }
}

// ---------------------------------------------------------------------------
// Pass 3: merge partial softmaxes, s = outH+outW+2, residual update in place.
// ---------------------------------------------------------------------------
__global__ __launch_bounds__(256) void merge_kernel(
    const float* __restrict__ T1, const float* __restrict__ S2,
    const float* __restrict__ mC, const float* __restrict__ sC,
    const float* __restrict__ mR, const float* __restrict__ sR,
    const float* __restrict__ g1p, const float* __restrict__ g2p,
    float* __restrict__ xe, float* __restrict__ xq)
{
    __shared__ float mc[128], sc[128], mr[128], sr[128];
    const int tid = threadIdx.x;
    const int h = blockIdx.x;
    const int b = blockIdx.y;
    if (tid < 128) {
        size_t o = ((size_t)b * 128 + h) * 128 + tid;
        mc[tid] = mC[o]; sc[tid] = sC[o];
        mr[tid] = mR[o]; sr[tid] = sR[o];
    }
    float g1 = g1p[0], g2 = g2p[0];
    __syncthreads();
    for (int i = tid; i < 8192; i += 256) {
        int c = i >> 7, w = i & 127;
        float oc_ = T1[(((size_t)b * 128 + w) * 64 + c) * 128 + h];
        float ow_ = S2[(((size_t)b * 64 + c) * 128 + h) * 128 + w];
        float m  = fmaxf(mc[w], mr[w]);
        float ec = __expf(mc[w] - m);
        float er = __expf(mr[w] - m);
        float denom = sc[w] * ec + sr[w] * er;
        float sval = (oc_ * ec + ow_ * er) / denom + 2.0f;
        size_t p = (((size_t)b * 64 + c) * 128 + h) * 128 + w;
        xe[p] += g1 * sval;
        xq[p] += g2 * sval;
    }
}

// ---------------------------------------------------------------------------
extern "C" void kernel_launch(void* const* d_in, const int* in_sizes, int n_in,
                              void* d_out, int out_size, void* d_ws, size_t ws_size,
                              hipStream_t stream)
{
    const float* x_ex = (const float*)d_in[0];
    const float* x_q  = (const float*)d_in[1];
    const float* cew  = (const float*)d_in[2];
    const float* bes  = (const float*)d_in[3];
    const float* beb  = (const float*)d_in[4];
    const float* cqw  = (const float*)d_in[5];
    const float* bqs  = (const float*)d_in[6];
    const float* bqb  = (const float*)d_in[7];
    const float* qw   = (const float*)d_in[8];
    const float* qb   = (const float*)d_in[9];
    const float* kw   = (const float*)d_in[10];
    const float* kb   = (const float*)d_in[11];
    const float* vw   = (const float*)d_in[12];
    const float* vb   = (const float*)d_in[13];
    const float* g1   = (const float*)d_in[14];
    const float* g2   = (const float*)d_in[15];
    const float* tew  = (const float*)d_in[16];
    const float* bts  = (const float*)d_in[17];
    const float* btb  = (const float*)d_in[18];
    const float* tqw  = (const float*)d_in[19];
    const float* btqs = (const float*)d_in[20];
    const float* btqb = (const float*)d_in[21];

    float* out = (float*)d_out;

    // workspace: [4 bf16 weight arrays | fp32 xe xq v q k]
    short* wt0 = (short*)d_ws;                 // head ex
    short* wt1 = wt0 + WT_ELEMS;               // head q
    short* wt2 = wt1 + WT_ELEMS;               // tail ex
    short* wt3 = wt2 + WT_ELEMS;               // tail q
    float* Wf  = (float*)(wt3 + WT_ELEMS);
    float* xe = Wf;
    float* xq = Wf + C64SZ;
    float* v  = Wf + 2 * C64SZ;
    float* q  = Wf + 3 * C64SZ;
    float* k  = q + QSZ;

    // d_out doubles as scratch for attention partials
    float* T1 = out;
    float* S2 = out + C64SZ;
    float* mC = out + 2 * C64SZ;
    float* sC = mC + STATSZ;
    float* mR = sC + STATSZ;
    float* sR = mR + STATSZ;

    // weight transforms (tiny)
    wprep_kernel<<<576, 256, 0, stream>>>(cew, wt0, 64, 256);
    wprep_kernel<<<576, 256, 0, stream>>>(cqw, wt1, 64, 256);
    wprep_kernel<<<576, 256, 0, stream>>>(tew, wt2, 256, 64);
    wprep_kernel<<<576, 256, 0, stream>>>(tqw, wt3, 256, 64);

    // head convs: 256 -> 64 (R=2 rows/block, 512 thr: 8 waves, NT=2)
    conv_mfma<256, 64, 2, 2, 512, 4><<<dim3(8, 64), 512, 0, stream>>>(x_ex, wt0, bes, beb, xe);
    conv_mfma<256, 64, 2, 2, 512, 4><<<dim3(8, 64), 512, 0, stream>>>(x_q,  wt1, bqs, bqb, xq);

    for (int round = 0; round < 2; ++round) {
        qk_kernel<<<512, 256, 0, stream>>>(xq, xe, qw, qb, kw, kb, q, k);
        v_kernel<<<dim3(512, 2), 256, 0, stream>>>(xe, vw, vb, v);
        attn_col_kernel<<<dim3(128, 8), 256, 0, stream>>>(q, k, v, T1, mC, sC);
        attn_row_kernel<<<dim3(128, 8), 256, 0, stream>>>(q, k, v, S2, mR, sR);
        merge_kernel<<<dim3(128, 8), 256, 0, stream>>>(T1, S2, mC, sC, mR, sR, g1, g2, xe, xq);
    }

    // tail convs: 64 -> 256 (R=1 row/block, 256 thr, NT=8)
    conv_mfma<64, 256, 1, 8, 256, 2><<<dim3(8, 128), 256, 0, stream>>>(xe, wt2, bts, btb, out);
    conv_mfma<64, 256, 1, 8, 256, 2><<<dim3(8, 128), 256, 0, stream>>>(xq, wt3, btqs, btqb, out + OUTHALF);
}

// Round 4
// 1397.661 us; speedup vs baseline: 1.1427x; 1.1427x over previous
//
#include <hip/hip_runtime.h>

// Sizes
constexpr int BB = 8;
constexpr int CC = 256;
constexpr int HH = 128;
constexpr int WW = 128;
constexpr int INTER = 64;
constexpr size_t NPIX = (size_t)HH * WW;            // 16384
constexpr size_t C64SZ = (size_t)BB * INTER * NPIX; // 8,388,608
constexpr size_t QSZ   = (size_t)BB * 8 * NPIX;     // 1,048,576
constexpr size_t STATSZ = (size_t)BB * HH * WW;     // 131,072
constexpr size_t OUTHALF = (size_t)BB * CC * NPIX;  // 33,554,432
constexpr size_t WT_ELEMS = (size_t)9 * 64 * 256;   // 147456 (same for head & tail)

typedef __attribute__((ext_vector_type(8))) __bf16 bf16x8;
typedef __attribute__((ext_vector_type(4))) float f32x4;
typedef __attribute__((ext_vector_type(4))) short short4v;
typedef __attribute__((ext_vector_type(8))) short short8v;

__device__ inline short f2bf(float f) {
    union { float f; unsigned u; } a; a.f = f;
    unsigned r = a.u + 0x7fffu + ((a.u >> 16) & 1u);   // RNE
    return (short)(r >> 16);
}

// ---------------------------------------------------------------------------
// Weight transform: wgt fp32 [OC][IC][3][3] -> wt bf16 [pos=dh*3+dw][OC][IC]
// ---------------------------------------------------------------------------
__global__ __launch_bounds__(256) void wprep_kernel(
    const float* __restrict__ wgt, short* __restrict__ wt, int OC, int IC)
{
    int idx = blockIdx.x * 256 + threadIdx.x;
    int n = 9 * OC * IC;
    if (idx >= n) return;
    int ic = idx & (IC - 1);
    int t  = idx / IC;
    int oc = t & (OC - 1);
    int pos = t / OC;
    wt[idx] = f2bf(wgt[((size_t)oc * IC + ic) * 9 + pos]);
}

// ---------------------------------------------------------------------------
// Activation convert: fp32 NCHW -> bf16 c32-blocked NHWC  [b][G][h][w][32]
// One block per (b, g, h): LDS transpose 32c x 128w.
// ---------------------------------------------------------------------------
template<int G>
__global__ __launch_bounds__(256) void cvt_kernel(
    const float* __restrict__ x, short* __restrict__ o)
{
    __shared__ float ts[32][133];   // pad 133: col reads stride 5 banks
    const int tid = threadIdx.x;
    const int h = blockIdx.x;
    const int g = blockIdx.y % G;
    const int b = blockIdx.y / G;

    // load: thread (c, w0) reads 16 w for its channel (coalesced)
    {
        int c  = tid >> 3;
        int w0 = (tid & 7) * 16;
        const float* src = x + ((size_t)(b * (G * 32) + g * 32 + c)) * NPIX + (size_t)h * 128 + w0;
#pragma unroll
        for (int j = 0; j < 4; ++j) {
            f32x4 vv = *(const f32x4*)(src + j * 4);
#pragma unroll
            for (int e = 0; e < 4; ++e) ts[c][w0 + j * 4 + e] = vv[e];
        }
    }
    __syncthreads();

    // store: thread (w, c8) packs 8 channels -> one b128 (coalesced: c8 fastest)
#pragma unroll
    for (int it = 0; it < 2; ++it) {
        int u  = it * 256 + tid;
        int c8 = u & 3;
        int w  = u >> 2;
        short8v pk;
#pragma unroll
        for (int j = 0; j < 8; ++j) pk[j] = f2bf(ts[c8 * 8 + j][w]);
        *(short8v*)(o + (((size_t)(b * G + g) * 128 + h) * 128 + w) * 32 + c8 * 8) = pk;
    }
}

// ---------------------------------------------------------------------------
// Conv 3x3 (pad 1) + BN + ReLU via bf16 MFMA implicit GEMM.
// Source activations: bf16 c32-blocked NHWC (from cvt_kernel) -> staging is
// pure b128 copy (no transpose, no cvt). Weights staged in LDS per chunk
// (XOR-swizzled slots, conflict-free reads) -> MFMA phase is LDS-only, so
// the xs prefetch global loads stay in flight across the whole phase.
// Each block: 64 oc x (R*128) pixels; grid z splits OC in 64-chunks.
// ---------------------------------------------------------------------------
template<int IC, int OC, int R, int NT, int BLK, int MINW>
__global__ __launch_bounds__(BLK, MINW) void conv_mfma(
    const short* __restrict__ xb,   // [b][IC/32][128][128][32] bf16
    const short* __restrict__ wt,   // [pos][OC][IC] bf16
    const float* __restrict__ bns, const float* __restrict__ bnb,
    float* __restrict__ out)
{
    constexpr int ROWS = R + 2;
    constexpr int NCH  = IC / 32;
    constexpr int NPIXT = R * 128;
    constexpr int NWN  = NPIXT / (NT * 16);       // waves along N (= all waves)
    constexpr int XSU  = ROWS * 512;              // staging units (row,col,quad)
    constexpr int NU   = XSU / BLK;               // units per thread
    constexpr int WSU  = 9 * 64 * 4;              // weight units (pos,oc,quad)
    constexpr int WIT  = (WSU + BLK - 1) / BLK;

    __shared__ __align__(16) short xs[ROWS * 130 * 40];
    __shared__ __align__(16) short ws[9 * 64 * 32];

    const int tid = threadIdx.x;
    const int b   = blockIdx.x;
    const int h0  = blockIdx.y * R;
    const int oc0b = blockIdx.z * 64;
    const int l   = tid & 63;
    const int ln  = l & 15;
    const int q   = l >> 4;
    const int wv  = tid >> 6;
    const int nbase = (wv % NWN) * (NT * 16);
    const int aoff  = (q ^ ((ln >> 1) & 3)) * 8;  // swizzled k-slot for weight reads

    f32x4 acc[4][NT];
#pragma unroll
    for (int mt = 0; mt < 4; ++mt)
#pragma unroll
        for (int nt = 0; nt < NT; ++nt)
            acc[mt][nt] = (f32x4){0.f, 0.f, 0.f, 0.f};

    // halo columns (outside image) zeroed once
    if (tid < ROWS * 8) {
        int row = tid >> 3;
        int rem = tid & 7;
        int colh = (rem >> 2) ? 129 : 0;
        int quad = rem & 3;
        short8v z = (short8v){0,0,0,0,0,0,0,0};
        *(short8v*)&xs[(row * 130 + colh) * 40 + quad * 8] = z;
    }

    short8v pf[NU];

    // ---- issue: global b128 loads for chunk ch (quad fastest -> coalesced) ----
    auto issue = [&](int ch) {
#pragma unroll
        for (int i = 0; i < NU; ++i) {
            int u    = i * BLK + tid;
            int quad = u & 3;
            int col  = (u >> 2) & 127;
            int row  = u >> 9;
            int grow = h0 - 1 + row;
            if ((unsigned)grow < 128u) {
                pf[i] = *(const short8v*)(xb +
                    (((size_t)(b * NCH + ch) * 128 + grow) * 128 + col) * 32 + quad * 8);
            } else {
                pf[i] = (short8v){0,0,0,0,0,0,0,0};
            }
        }
    };

    // ---- commit: b128 LDS writes ----
    auto commit = [&]() {
#pragma unroll
        for (int i = 0; i < NU; ++i) {
            int u    = i * BLK + tid;
            int quad = u & 3;
            int col  = (u >> 2) & 127;
            int row  = u >> 9;
            *(short8v*)&xs[(row * 130 + col + 1) * 40 + quad * 8] = pf[i];
        }
    };

    // ---- stage weights for chunk ch into LDS (swizzled slots) ----
    auto stage_ws = [&](int ch) {
#pragma unroll
        for (int it = 0; it < WIT; ++it) {
            int u = it * BLK + tid;
            if (u < WSU) {
                int quad = u & 3;
                int oc   = (u >> 2) & 63;
                int pos  = u >> 8;
                short8v wv8 = *(const short8v*)(wt +
                    (size_t)(pos * OC + oc0b + oc) * IC + ch * 32 + quad * 8);
                int row  = pos * 64 + oc;
                int slot = quad ^ ((row >> 1) & 3);
                *(short8v*)&ws[row * 32 + slot * 8] = wv8;
            }
        }
    };

    // prologue: stage chunk 0 (activations + weights)
    issue(0);
    commit();
    stage_ws(0);
    __syncthreads();

    for (int ch = 0; ch < NCH; ++ch) {
        // issue next chunk's activation loads; they stay outstanding through
        // the (LDS-only) MFMA phase below.
        if (ch + 1 < NCH) issue(ch + 1);

        for (int dh = 0; dh < 3; ++dh) {
#pragma unroll
            for (int dw = 0; dw < 3; ++dw) {
                const int pos = dh * 3 + dw;
                bf16x8 a[4];
#pragma unroll
                for (int mt = 0; mt < 4; ++mt)
                    a[mt] = *(const bf16x8*)&ws[(pos * 64 + mt * 16 + ln) * 32 + aoff];
#pragma unroll
                for (int nt = 0; nt < NT; ++nt) {
                    int pix  = nbase + nt * 16 + ln;
                    int rowi = (pix >> 7) + dh;
                    int wpos = (pix & 127) + dw;
                    bf16x8 bfr = *(const bf16x8*)&xs[(rowi * 130 + wpos) * 40 + q * 8];
#pragma unroll
                    for (int mt = 0; mt < 4; ++mt)
                        acc[mt][nt] = __builtin_amdgcn_mfma_f32_16x16x32_bf16(
                            a[mt], bfr, acc[mt][nt], 0, 0, 0);
                }
            }
        }
        __syncthreads();
        if (ch + 1 < NCH) {
            commit();
            stage_ws(ch + 1);
            __syncthreads();
        }
    }

    // ---- epilogue: BN + ReLU, store fp32 NCHW ----
#pragma unroll
    for (int mt = 0; mt < 4; ++mt) {
#pragma unroll
        for (int r = 0; r < 4; ++r) {
            int oc = oc0b + mt * 16 + q * 4 + r;
            float s   = bns[oc];
            float bb2 = bnb[oc];
#pragma unroll
            for (int nt = 0; nt < NT; ++nt) {
                int pix = nbase + nt * 16 + ln;
                int h = h0 + (pix >> 7), w = pix & 127;
                float v = fmaxf(acc[mt][nt][r] * s + bb2, 0.f);
                out[(((size_t)b * OC + oc) * 128 + h) * 128 + w] = v;
            }
        }
    }
}

// ---------------------------------------------------------------------------
// QK projection: q = q_w @ xq + q_b (8 ch), k = k_w @ xe + k_b (8 ch)
// ---------------------------------------------------------------------------
__global__ __launch_bounds__(256) void qk_kernel(
    const float* __restrict__ xq, const float* __restrict__ xe,
    const float* __restrict__ qw, const float* __restrict__ qb,
    const float* __restrict__ kw, const float* __restrict__ kb,
    float* __restrict__ q, float* __restrict__ k)
{
    size_t p = (size_t)blockIdx.x * 256 + threadIdx.x;
    int b = (int)(p >> 14);
    int pix = (int)(p & 16383);
    const float* xqb = xq + (size_t)b * 64 * NPIX + pix;
    const float* xeb = xe + (size_t)b * 64 * NPIX + pix;
    float qa[8], ka[8];
#pragma unroll
    for (int o = 0; o < 8; ++o) { qa[o] = qb[o]; ka[o] = kb[o]; }
    for (int c = 0; c < 64; ++c) {
        float xv = xqb[(size_t)c * NPIX];
        float ev = xeb[(size_t)c * NPIX];
#pragma unroll
        for (int o = 0; o < 8; ++o) {
            qa[o] += qw[o * 64 + c] * xv;
            ka[o] += kw[o * 64 + c] * ev;
        }
    }
#pragma unroll
    for (int o = 0; o < 8; ++o) {
        q[((size_t)b * 8 + o) * NPIX + pix] = qa[o];
        k[((size_t)b * 8 + o) * NPIX + pix] = ka[o];
    }
}

// ---------------------------------------------------------------------------
// V projection: v = v_w @ xe + v_b (64 ch), 32 oc per z-slice
// ---------------------------------------------------------------------------
__global__ __launch_bounds__(256) void v_kernel(
    const float* __restrict__ xe,
    const float* __restrict__ vw, const float* __restrict__ vb,
    float* __restrict__ v)
{
    size_t p = (size_t)blockIdx.x * 256 + threadIdx.x;
    int b = (int)(p >> 14);
    int pix = (int)(p & 16383);
    int oc0 = blockIdx.y * 32;
    const float* xeb = xe + (size_t)b * 64 * NPIX + pix;
    float acc[32];
#pragma unroll
    for (int o = 0; o < 32; ++o) acc[o] = vb[oc0 + o];
    for (int c = 0; c < 64; ++c) {
        float ev = xeb[(size_t)c * NPIX];
#pragma unroll
        for (int o = 0; o < 32; ++o) acc[o] += vw[(oc0 + o) * 64 + c] * ev;
    }
#pragma unroll
    for (int o = 0; o < 32; ++o)
        v[((size_t)b * 64 + oc0 + o) * NPIX + pix] = acc[o];
}

// ---------------------------------------------------------------------------
// Pass 1: column attention partials.
// ---------------------------------------------------------------------------
__global__ __launch_bounds__(256) void attn_col_kernel(
    const float* __restrict__ q, const float* __restrict__ k,
    const float* __restrict__ v,
    float* __restrict__ outT, float* __restrict__ mC, float* __restrict__ sC)
{
    __shared__ float qs[8][128];
    __shared__ float ks[8][128];
    __shared__ float vs[64][129];
    __shared__ float E[32][129];

    const int tid = threadIdx.x;
    const int w = blockIdx.x;
    const int b = blockIdx.y;

    for (int i = tid; i < 1024; i += 256) {
        int c = i >> 7, h = i & 127;
        qs[c][h] = q[(((size_t)b * 8 + c) * 128 + h) * 128 + w];
        ks[c][h] = k[(((size_t)b * 8 + c) * 128 + h) * 128 + w];
    }
    for (int i = tid; i < 8192; i += 256) {
        int c = i >> 7, j = i & 127;
        vs[c][j] = v[(((size_t)b * 64 + c) * 128 + j) * 128 + w];
    }
    __syncthreads();

    const int jj = tid & 127;
    const int hi = tid >> 7;

    for (int hc = 0; hc < 4; ++hc) {
        const int h0 = hc * 32;
#pragma unroll
        for (int e = 0; e < 16; ++e) {
            int i = e * 2 + hi;
            float a = 0.f;
#pragma unroll
            for (int c = 0; c < 8; ++c) a += qs[c][h0 + i] * ks[c][jj];
            if (h0 + i == jj) a = -1e30f;
            E[i][jj] = a;
        }
        __syncthreads();
        // ---- wave-parallel softmax: 8 lanes per row, shfl_xor reduce ----
        {
            int row = tid >> 3, l8 = tid & 7;
            float m = -1e30f;
#pragma unroll
            for (int t = 0; t < 16; ++t) m = fmaxf(m, E[row][l8 + t * 8]);
            m = fmaxf(m, __shfl_xor(m, 1));
            m = fmaxf(m, __shfl_xor(m, 2));
            m = fmaxf(m, __shfl_xor(m, 4));
            float s = 0.f;
#pragma unroll
            for (int t = 0; t < 16; ++t) {
                int j = l8 + t * 8;
                float pp = __expf(E[row][j] - m);
                E[row][j] = pp;
                s += pp;
            }
            s += __shfl_xor(s, 1);
            s += __shfl_xor(s, 2);
            s += __shfl_xor(s, 4);
            if (l8 == 0) {
                mC[((size_t)b * 128 + (h0 + row)) * 128 + w] = m;
                sC[((size_t)b * 128 + (h0 + row)) * 128 + w] = s;
            }
        }
        __syncthreads();
        {
            int c0 = (tid & 15) * 4;
            int i0 = (tid >> 4) * 2;
            float acc[4][2];
#pragma unroll
            for (int a = 0; a < 4; ++a) { acc[a][0] = 0.f; acc[a][1] = 0.f; }
            for (int j = 0; j < 128; ++j) {
                float p0 = E[i0][j], p1 = E[i0 + 1][j];
#pragma unroll
                for (int a = 0; a < 4; ++a) {
                    float vv = vs[c0 + a][j];
                    acc[a][0] += vv * p0;
                    acc[a][1] += vv * p1;
                }
            }
#pragma unroll
            for (int a = 0; a < 4; ++a) {
                size_t base = (((size_t)b * 128 + w) * 64 + (c0 + a)) * 128 + h0 + i0;
                outT[base]     = acc[a][0];
                outT[base + 1] = acc[a][1];
            }
        }
        __syncthreads();
    }
}

// ---------------------------------------------------------------------------
// Pass 2: row attention partials.
// ---------------------------------------------------------------------------
__global__ __launch_bounds__(256) void attn_row_kernel(
    const float* __restrict__ q, const float* __restrict__ k,
    const float* __restrict__ v,
    float* __restrict__ outS, float* __restrict__ mR, float* __restrict__ sR)
{
    __shared__ float qs[8][128];
    __shared__ float ks[8][128];
    __shared__ float vs[64][129];
    __shared__ float E[32][129];

    const int tid = threadIdx.x;
    const int h = blockIdx.x;
    const int b = blockIdx.y;

    for (int i = tid; i < 1024; i += 256) {
        int c = i >> 7, x = i & 127;
        qs[c][x] = q[(((size_t)b * 8 + c) * 128 + h) * 128 + x];
        ks[c][x] = k[(((size_t)b * 8 + c) * 128 + h) * 128 + x];
    }
    for (int i = tid; i < 8192; i += 256) {
        int c = i >> 7, j = i & 127;
        vs[c][j] = v[(((size_t)b * 64 + c) * 128 + h) * 128 + j];
    }
    __syncthreads();

    const int jj = tid & 127;
    const int hi = tid >> 7;

    for (int wc = 0; wc < 4; ++wc) {
        const int w0 = wc * 32;
#pragma unroll
        for (int e = 0; e < 16; ++e) {
            int i = e * 2 + hi;
            float a = 0.f;
#pragma unroll
            for (int c = 0; c < 8; ++c) a += qs[c][w0 + i] * ks[c][jj];
            E[i][jj] = a;
        }
        __syncthreads();
        // ---- wave-parallel softmax ----
        {
            int row = tid >> 3, l8 = tid & 7;
            float m = -1e30f;
#pragma unroll
            for (int t = 0; t < 16; ++t) m = fmaxf(m, E[row][l8 + t * 8]);
            m = fmaxf(m, __shfl_xor(m, 1));
            m = fmaxf(m, __shfl_xor(m, 2));
            m = fmaxf(m, __shfl_xor(m, 4));
            float s = 0.f;
#pragma unroll
            for (int t = 0; t < 16; ++t) {
                int j = l8 + t * 8;
                float pp = __expf(E[row][j] - m);
                E[row][j] = pp;
                s += pp;
            }
            s += __shfl_xor(s, 1);
            s += __shfl_xor(s, 2);
            s += __shfl_xor(s, 4);
            if (l8 == 0) {
                mR[((size_t)b * 128 + h) * 128 + (w0 + row)] = m;
                sR[((size_t)b * 128 + h) * 128 + (w0 + row)] = s;
            }
        }
        __syncthreads();
        {
            int c0 = (tid & 15) * 4;
            int i0 = (tid >> 4) * 2;
            float acc[4][2];
#pragma unroll
            for (int a = 0; a < 4; ++a) { acc[a][0] = 0.f; acc[a][1] = 0.f; }
            for (int j = 0; j < 128; ++j) {
                float p0 = E[i0][j], p1 = E[i0 + 1][j];
#pragma unroll
                for (int a = 0; a < 4; ++a) {
                    float vv = vs[c0 + a][j];
                    acc[a][0] += vv * p0;
                    acc[a][1] += vv * p1;
                }
            }
#pragma unroll
            for (int a = 0; a < 4; ++a) {
                size_t base = (((size_t)b * 64 + (c0 + a)) * 128 + h) * 128 + w0 + i0;
                outS[base]     = acc[a][0];
                outS[base + 1] = acc[a][1];
            }
        }
        __syncthreads();
    }
}

// ---------------------------------------------------------------------------
// Pass 3: merge partial softmaxes, s = outH+outW+2, residual update in place.
// ---------------------------------------------------------------------------
__global__ __launch_bounds__(256) void merge_kernel(
    const float* __restrict__ T1, const float* __restrict__ S2,
    const float* __restrict__ mC, const float* __restrict__ sC,
    const float* __restrict__ mR, const float* __restrict__ sR,
    const float* __restrict__ g1p, const float* __restrict__ g2p,
    float* __restrict__ xe, float* __restrict__ xq)
{
    __shared__ float mc[128], sc[128], mr[128], sr[128];
    const int tid = threadIdx.x;
    const int h = blockIdx.x;
    const int b = blockIdx.y;
    if (tid < 128) {
        size_t o = ((size_t)b * 128 + h) * 128 + tid;
        mc[tid] = mC[o]; sc[tid] = sC[o];
        mr[tid] = mR[o]; sr[tid] = sR[o];
    }
    float g1 = g1p[0], g2 = g2p[0];
    __syncthreads();
    for (int i = tid; i < 8192; i += 256) {
        int c = i >> 7, w = i & 127;
        float oc_ = T1[(((size_t)b * 128 + w) * 64 + c) * 128 + h];
        float ow_ = S2[(((size_t)b * 64 + c) * 128 + h) * 128 + w];
        float m  = fmaxf(mc[w], mr[w]);
        float ec = __expf(mc[w] - m);
        float er = __expf(mr[w] - m);
        float denom = sc[w] * ec + sr[w] * er;
        float sval = (oc_ * ec + ow_ * er) / denom + 2.0f;
        size_t p = (((size_t)b * 64 + c) * 128 + h) * 128 + w;
        xe[p] += g1 * sval;
        xq[p] += g2 * sval;
    }
}

// ---------------------------------------------------------------------------
extern "C" void kernel_launch(void* const* d_in, const int* in_sizes, int n_in,
                              void* d_out, int out_size, void* d_ws, size_t ws_size,
                              hipStream_t stream)
{
    const float* x_ex = (const float*)d_in[0];
    const float* x_q  = (const float*)d_in[1];
    const float* cew  = (const float*)d_in[2];
    const float* bes  = (const float*)d_in[3];
    const float* beb  = (const float*)d_in[4];
    const float* cqw  = (const float*)d_in[5];
    const float* bqs  = (const float*)d_in[6];
    const float* bqb  = (const float*)d_in[7];
    const float* qw   = (const float*)d_in[8];
    const float* qb   = (const float*)d_in[9];
    const float* kw   = (const float*)d_in[10];
    const float* kb   = (const float*)d_in[11];
    const float* vw   = (const float*)d_in[12];
    const float* vb   = (const float*)d_in[13];
    const float* g1   = (const float*)d_in[14];
    const float* g2   = (const float*)d_in[15];
    const float* tew  = (const float*)d_in[16];
    const float* bts  = (const float*)d_in[17];
    const float* btb  = (const float*)d_in[18];
    const float* tqw  = (const float*)d_in[19];
    const float* btqs = (const float*)d_in[20];
    const float* btqb = (const float*)d_in[21];

    float* out = (float*)d_out;

    // workspace: [4 bf16 weight arrays | fp32 xe xq v q k | bf16 xeb16 xqb16]
    short* wt0 = (short*)d_ws;                 // head ex
    short* wt1 = wt0 + WT_ELEMS;               // head q
    short* wt2 = wt1 + WT_ELEMS;               // tail ex
    short* wt3 = wt2 + WT_ELEMS;               // tail q
    float* Wf  = (float*)(wt3 + WT_ELEMS);
    float* xe = Wf;
    float* xq = Wf + C64SZ;
    float* v  = Wf + 2 * C64SZ;
    float* q  = Wf + 3 * C64SZ;
    float* k  = q + QSZ;
    short* xeb16 = (short*)(k + QSZ);          // bf16 blocked xe for tail conv
    short* xqb16 = xeb16 + C64SZ;              // (C64SZ shorts each)

    // d_out doubles as scratch:
    //  - before attention: bf16 blocked head inputs (2 x 67MB)
    //  - during attention: partials T1/S2/stats
    short* xb16e = (short*)out;
    short* xb16q = xb16e + (size_t)BB * CC * NPIX;
    float* T1 = out;
    float* S2 = out + C64SZ;
    float* mC = out + 2 * C64SZ;
    float* sC = mC + STATSZ;
    float* mR = sC + STATSZ;
    float* sR = mR + STATSZ;

    // weight transforms (tiny)
    wprep_kernel<<<576, 256, 0, stream>>>(cew, wt0, 64, 256);
    wprep_kernel<<<576, 256, 0, stream>>>(cqw, wt1, 64, 256);
    wprep_kernel<<<576, 256, 0, stream>>>(tew, wt2, 256, 64);
    wprep_kernel<<<576, 256, 0, stream>>>(tqw, wt3, 256, 64);

    // convert head inputs fp32 NCHW -> bf16 c32-blocked NHWC
    cvt_kernel<8><<<dim3(128, 64), 256, 0, stream>>>(x_ex, xb16e);
    cvt_kernel<8><<<dim3(128, 64), 256, 0, stream>>>(x_q,  xb16q);

    // head convs: 256 -> 64 (R=2 rows/block, 512 thr = 8 waves, NT=2)
    conv_mfma<256, 64, 2, 2, 512, 4><<<dim3(8, 64, 1), 512, 0, stream>>>(xb16e, wt0, bes, beb, xe);
    conv_mfma<256, 64, 2, 2, 512, 4><<<dim3(8, 64, 1), 512, 0, stream>>>(xb16q, wt1, bqs, bqb, xq);

    for (int round = 0; round < 2; ++round) {
        qk_kernel<<<512, 256, 0, stream>>>(xq, xe, qw, qb, kw, kb, q, k);
        v_kernel<<<dim3(512, 2), 256, 0, stream>>>(xe, vw, vb, v);
        attn_col_kernel<<<dim3(128, 8), 256, 0, stream>>>(q, k, v, T1, mC, sC);
        attn_row_kernel<<<dim3(128, 8), 256, 0, stream>>>(q, k, v, S2, mR, sR);
        merge_kernel<<<dim3(128, 8), 256, 0, stream>>>(T1, S2, mC, sC, mR, sR, g1, g2, xe, xq);
    }

    // convert xe/xq -> bf16 blocked for tail convs
    cvt_kernel<2><<<dim3(128, 16), 256, 0, stream>>>(xe, xeb16);
    cvt_kernel<2><<<dim3(128, 16), 256, 0, stream>>>(xq, xqb16);

    // tail convs: 64 -> 256 (R=1 row/block, 256 thr, NT=2, oc split x4)
    conv_mfma<64, 256, 1, 2, 256, 2><<<dim3(8, 128, 4), 256, 0, stream>>>(xeb16, wt2, bts, btb, out);
    conv_mfma<64, 256, 1, 2, 256, 2><<<dim3(8, 128, 4), 256, 0, stream>>>(xqb16, wt3, btqs, btqb, out + OUTHALF);
}